// Round 6
// baseline (1410.443 us; speedup 1.0000x reference)
//
#include <hip/hip_runtime.h>
#include <math.h>

typedef unsigned short u16;
typedef short s16x8 __attribute__((ext_vector_type(8)));
typedef float f32x4 __attribute__((ext_vector_type(4)));
typedef float f32x16 __attribute__((ext_vector_type(16)));

#define GLOAD16(gp, lp)                                                        \
  __builtin_amdgcn_global_load_lds(                                            \
      (const __attribute__((address_space(1))) void*)(gp),                     \
      (__attribute__((address_space(3))) void*)(lp), 16, 0, 0)

__device__ __forceinline__ u16 f2bf(float f) {
  union { float f; unsigned u; } v; v.f = f;
  unsigned r = v.u + 0x7fffu + ((v.u >> 16) & 1u);  // RNE
  return (u16)(r >> 16);
}

// ---------------- kernel 1: x fp32 -> bf16 ----------------
__global__ __launch_bounds__(256) void cvt_x_kernel(const float* __restrict__ in,
                                                    u16* __restrict__ out) {
  size_t i = ((size_t)blockIdx.x * 256 + threadIdx.x) * 8;
  float4 a = *(const float4*)(in + i);
  float4 b = *(const float4*)(in + i + 4);
  s16x8 v;
  v[0] = (short)f2bf(a.x); v[1] = (short)f2bf(a.y);
  v[2] = (short)f2bf(a.z); v[3] = (short)f2bf(a.w);
  v[4] = (short)f2bf(b.x); v[5] = (short)f2bf(b.y);
  v[6] = (short)f2bf(b.z); v[7] = (short)f2bf(b.w);
  *(s16x8*)(out + i) = v;
}

// ------- kernel 2: transpose+cvt. mats 0-3 (g/u) -> interleaved GU with
// 128-row blocking: GU row = (f>>7)*256 + t*128 + (f&127), t=0 gate, 1 up.
// mats 4,5 plain transpose.
__global__ __launch_bounds__(256) void transpose_cvt_kernel(
    const float* __restrict__ in0, const float* __restrict__ in1,
    const float* __restrict__ in2, const float* __restrict__ in3,
    const float* __restrict__ in4, const float* __restrict__ in5,
    u16* __restrict__ o01, u16* __restrict__ o23,
    u16* __restrict__ o4, u16* __restrict__ o5) {
  __shared__ float s[64 * 65];
  const int mat = blockIdx.y;
  const float* in; u16* out;
  switch (mat) {
    case 0: in = in0; out = o01; break;
    case 1: in = in1; out = o01; break;
    case 2: in = in2; out = o23; break;
    case 3: in = in3; out = o23; break;
    case 4: in = in4; out = o4; break;
    default: in = in5; out = o5; break;
  }
  const int R = (mat < 4) ? 4096 : 11008;
  const int C = (mat < 4) ? 11008 : 4096;
  const int nTc = C >> 6;
  const int tr = blockIdx.x / nTc, tc = blockIdx.x - tr * nTc;
  const int r0 = tr << 6, c0 = tc << 6;
  const int t = threadIdx.x;
#pragma unroll
  for (int p = 0; p < 4; ++p) {
    const int lr = p * 16 + (t >> 4);
    const int lc = (t & 15) * 4;
    float4 v = *(const float4*)(in + (size_t)(r0 + lr) * C + (c0 + lc));
    float* sp = &s[lr * 65 + lc];
    sp[0] = v.x; sp[1] = v.y; sp[2] = v.z; sp[3] = v.w;
  }
  __syncthreads();
#pragma unroll
  for (int q = 0; q < 2; ++q) {
    const int oc = q * 32 + (t >> 3);
    const int orr = (t & 7) * 8;
    s16x8 v;
#pragma unroll
    for (int i = 0; i < 8; ++i) v[i] = (short)f2bf(s[(orr + i) * 65 + oc]);
    const int f = c0 + oc;
    size_t orow;
    if (mat < 4) orow = (size_t)((f >> 7) << 8) + ((mat & 1) << 7) + (f & 127);
    else         orow = (size_t)f;
    *(s16x8*)(out + orow * R + (r0 + orr)) = v;
  }
}

// ======== 256x256 GEMM core, 32x32x16 MFMA, 3-barrier/K-tile schedule =======
// 8 waves (2M x 4N). Per wave: 4 m-frags (mh,fj) of 32 rows, 2 n-frags (nh) of
// 32 cols (nh = B half). Frag-once ds_reads. LDS [2buf][2half][128][64] u16
// per operand, 16B-chunk XOR swizzle (pre-swizzled global source).
// K-tile phases: P1{rd af(mh0)+bf(0); stg A0'; MFMA(0,0); vm4; bar}
//                P2{rd bf(1); stg B0'; MFMA(0,1); vm4; bar}
//                P34{rd af(mh1); stg B1'; MFMA(1,1); stg A1'; MFMA(1,0); vm4; bar}
// vmcnt(4) drains exactly the halves the next phase's header reads.
#define SBAR() __builtin_amdgcn_s_barrier()
#define LGKM0() asm volatile("s_waitcnt lgkmcnt(0)")
#define VMCNT4() asm volatile("s_waitcnt vmcnt(4)")
#define VMCNT2() asm volatile("s_waitcnt vmcnt(2)")
#define VMCNT0() asm volatile("s_waitcnt vmcnt(0)")

#define LDA(d, mh)                                                             \
  do {                                                                         \
    _Pragma("unroll") for (int fj = 0; fj < 2; ++fj)                           \
        _Pragma("unroll") for (int ks = 0; ks < 4; ++ks)                       \
        af[fj][ks] = *(const s16x8*)(ldsA + (d) * 32768 + (mh) * 16384 +       \
                                     arow + fj * 4096 + cx[ks]);               \
  } while (0)
#define LDB(d, nh)                                                             \
  do {                                                                         \
    _Pragma("unroll") for (int ks = 0; ks < 4; ++ks)                           \
        bf[nh][ks] = *(const s16x8*)(ldsB + (d) * 32768 + (nh) * 16384 +       \
                                     brow + cx[ks]);                           \
  } while (0)
#define MFMA8(mh, nh)                                                          \
  do {                                                                         \
    __builtin_amdgcn_s_setprio(1);                                             \
    _Pragma("unroll") for (int fj = 0; fj < 2; ++fj)                           \
        _Pragma("unroll") for (int ks = 0; ks < 4; ++ks)                       \
        acc[mh][fj][nh] = __builtin_amdgcn_mfma_f32_32x32x16_bf16(             \
            af[fj][ks], bf[nh][ks], acc[mh][fj][nh], 0, 0, 0);                 \
    __builtin_amdgcn_s_setprio(0);                                             \
  } while (0)

#define STG_A(d, h, kt)                                                        \
  do {                                                                         \
    GLOAD16(srcA + (size_t)((h) * 128) * KB + (size_t)(kt) * 128,              \
            ldsA + (d) * 32768 + (h) * 16384 + woff);                          \
    GLOAD16(srcA + (size_t)((h) * 128 + 64) * KB + (size_t)(kt) * 128,         \
            ldsA + (d) * 32768 + (h) * 16384 + 8192 + woff);                   \
  } while (0)
#define STG_B(d, h, kt)                                                        \
  do {                                                                         \
    GLOAD16(srcB + (size_t)((h) * 128) * KB + (size_t)(kt) * 128,              \
            ldsB + (d) * 32768 + (h) * 16384 + woff);                          \
    GLOAD16(srcB + (size_t)((h) * 128 + 64) * KB + (size_t)(kt) * 128,         \
            ldsB + (d) * 32768 + (h) * 16384 + 8192 + woff);                   \
  } while (0)

// ---------------- persistent gate+up GEMM + silu (atomic work queue) --------
__global__ __launch_bounds__(512, 1) void gemm_gateup_persist(
    const u16* __restrict__ A, const u16* __restrict__ GUl,
    const u16* __restrict__ GUv, const int* __restrict__ tt,
    u16* __restrict__ H, int* __restrict__ qcnt) {
  constexpr int KB = 8192;   // bytes per K-row
  constexpr int NKT = 64;    // K-tiles of 64
  __shared__ u16 sA[2][2][128][64];
  __shared__ u16 sB[2][2][128][64];
  __shared__ int sQ;

  const int t = threadIdx.x;
  const int lane = t & 63;
  const int l31 = lane & 31;
  const int kg = lane >> 5;
  const int wn = (t >> 6) & 3;
  const int wm = (t >> 8) & 1;

  const int rowq = t >> 3;
  const int gsw = ((t & 7) ^ (rowq & 7)) << 4;
  char* ldsA = (char*)&sA[0][0][0][0];
  char* ldsB = (char*)&sB[0][0][0][0];
  const int woff = (t & 448) << 4;

  const int arow = (wm * 64 + l31) * 128;
  const int brow = (wn * 32 + l31) * 128;
  int cx[4];
#pragma unroll
  for (int ks = 0; ks < 4; ++ks) cx[ks] = ((2 * ks + kg) ^ (lane & 7)) << 4;

  for (;;) {
    __syncthreads();
    if (t == 0) sQ = atomicAdd(qcnt, 1);
    __syncthreads();
    const int q = sQ;
    if (q >= 1376) break;
    const int nT = q >> 4;
    const int mT = q & 15;
    const int side = tt[mT << 8];
    const u16* GU = side ? GUl : GUv;
    const char* srcA = (const char*)A + (size_t)(mT * 256 + rowq) * KB + gsw;
    const char* srcB = (const char*)GU + (size_t)(nT * 256 + rowq) * KB + gsw;

    s16x8 af[2][4], bf[2][4];
    f32x16 acc[2][2][2];
#pragma unroll
    for (int a = 0; a < 2; ++a)
#pragma unroll
      for (int b = 0; b < 2; ++b)
#pragma unroll
        for (int c = 0; c < 2; ++c)
#pragma unroll
          for (int r = 0; r < 16; ++r) acc[a][b][c][r] = 0.f;

    // prologue: tile0 halves in order A0,B0,B1,A1
    STG_A(0, 0, 0); STG_B(0, 0, 0); STG_B(0, 1, 0); STG_A(0, 1, 0);
    VMCNT4();
    SBAR();

    for (int T = 0; T < NKT - 1; ++T) {
      const int d = T & 1, nd = d ^ 1;
      // P1
      LDA(d, 0); LDB(d, 0);
      STG_A(nd, 0, T + 1);
      LGKM0(); MFMA8(0, 0);
      VMCNT4(); SBAR();
      // P2
      LDB(d, 1);
      STG_B(nd, 0, T + 1);
      LGKM0(); MFMA8(0, 1);
      VMCNT4(); SBAR();
      // P3+P4
      LDA(d, 1);
      STG_B(nd, 1, T + 1);
      LGKM0(); MFMA8(1, 1);
      STG_A(nd, 1, T + 1);
      MFMA8(1, 0);
      VMCNT4(); SBAR();
    }
    {  // tail K-tile (no staging)
      const int d = (NKT - 1) & 1;
      LDA(d, 0); LDB(d, 0);
      LGKM0(); MFMA8(0, 0);
      VMCNT2(); SBAR();
      LDB(d, 1);
      LGKM0(); MFMA8(0, 1);
      VMCNT0(); SBAR();
      LDA(d, 1);
      LGKM0(); MFMA8(1, 1);
      MFMA8(1, 0);
    }

    // epilogue: silu(gate)*up -> H (nh0 = gate, nh1 = up; same f in-lane)
    const int f = nT * 128 + wn * 32 + l31;
#pragma unroll
    for (int mh = 0; mh < 2; ++mh)
#pragma unroll
      for (int fj = 0; fj < 2; ++fj) {
        const int rowbase = mT * 256 + mh * 128 + wm * 64 + fj * 32 + 4 * kg;
#pragma unroll
        for (int r = 0; r < 16; ++r) {
          const int row = rowbase + (r & 3) + 8 * (r >> 2);
          const float gv = acc[mh][fj][0][r];
          const float uv = acc[mh][fj][1][r];
          const float hv = gv / (1.f + __expf(-gv)) * uv;
          H[(size_t)row * 11008 + f] = f2bf(hv);
        }
      }
  }
}

// ---------------- down GEMM (static 1 tile/block) ----------------
__global__ __launch_bounds__(512, 1) void gemm_down(
    const u16* __restrict__ Hm, const u16* __restrict__ Dl,
    const u16* __restrict__ Dv, const int* __restrict__ tt,
    float* __restrict__ O) {
  constexpr int KB = 22016;  // bytes per K-row
  constexpr int NKT = 172;
  __shared__ u16 sA[2][2][128][64];
  __shared__ u16 sB[2][2][128][64];

  const int bid = blockIdx.x;
  const int wg = (bid & 7) * 32 + (bid >> 3);  // bijective XCD swizzle
  const int mT = wg & 15;
  const int nT = wg >> 4;

  const int t = threadIdx.x;
  const int lane = t & 63;
  const int l31 = lane & 31;
  const int kg = lane >> 5;
  const int wn = (t >> 6) & 3;
  const int wm = (t >> 8) & 1;

  const int side = tt[mT << 8];
  const u16* B = side ? Dl : Dv;

  const int rowq = t >> 3;
  const int gsw = ((t & 7) ^ (rowq & 7)) << 4;
  const char* srcA = (const char*)Hm + (size_t)(mT * 256 + rowq) * KB + gsw;
  const char* srcB = (const char*)B + (size_t)(nT * 256 + rowq) * KB + gsw;
  char* ldsA = (char*)&sA[0][0][0][0];
  char* ldsB = (char*)&sB[0][0][0][0];
  const int woff = (t & 448) << 4;

  const int arow = (wm * 64 + l31) * 128;
  const int brow = (wn * 32 + l31) * 128;
  int cx[4];
#pragma unroll
  for (int ks = 0; ks < 4; ++ks) cx[ks] = ((2 * ks + kg) ^ (lane & 7)) << 4;

  s16x8 af[2][4], bf[2][4];
  f32x16 acc[2][2][2];
#pragma unroll
  for (int a = 0; a < 2; ++a)
#pragma unroll
    for (int b = 0; b < 2; ++b)
#pragma unroll
      for (int c = 0; c < 2; ++c)
#pragma unroll
        for (int r = 0; r < 16; ++r) acc[a][b][c][r] = 0.f;

  STG_A(0, 0, 0); STG_B(0, 0, 0); STG_B(0, 1, 0); STG_A(0, 1, 0);
  VMCNT4();
  SBAR();

  for (int T = 0; T < NKT - 1; ++T) {
    const int d = T & 1, nd = d ^ 1;
    LDA(d, 0); LDB(d, 0);
    STG_A(nd, 0, T + 1);
    LGKM0(); MFMA8(0, 0);
    VMCNT4(); SBAR();
    LDB(d, 1);
    STG_B(nd, 0, T + 1);
    LGKM0(); MFMA8(0, 1);
    VMCNT4(); SBAR();
    LDA(d, 1);
    STG_B(nd, 1, T + 1);
    LGKM0(); MFMA8(1, 1);
    STG_A(nd, 1, T + 1);
    MFMA8(1, 0);
    VMCNT4(); SBAR();
  }
  {
    const int d = (NKT - 1) & 1;
    LDA(d, 0); LDB(d, 0);
    LGKM0(); MFMA8(0, 0);
    VMCNT2(); SBAR();
    LDB(d, 1);
    LGKM0(); MFMA8(0, 1);
    VMCNT0(); SBAR();
    LDA(d, 1);
    LGKM0(); MFMA8(1, 1);
    MFMA8(1, 0);
  }

#pragma unroll
  for (int mh = 0; mh < 2; ++mh)
#pragma unroll
    for (int fj = 0; fj < 2; ++fj) {
      const int rowbase = mT * 256 + mh * 128 + wm * 64 + fj * 32 + 4 * kg;
#pragma unroll
      for (int nh = 0; nh < 2; ++nh) {
        const int col = nT * 256 + nh * 128 + wn * 32 + l31;
#pragma unroll
        for (int r = 0; r < 16; ++r) {
          const int row = rowbase + (r & 3) + 8 * (r >> 2);
          O[(size_t)row * 4096 + col] = acc[mh][fj][nh][r];
        }
      }
    }
}

extern "C" void kernel_launch(void* const* d_in, const int* in_sizes, int n_in,
                              void* d_out, int out_size, void* d_ws, size_t ws_size,
                              hipStream_t stream) {
  (void)in_sizes; (void)n_in; (void)out_size; (void)ws_size;
  const float* x  = (const float*)d_in[0];
  const int*   tt = (const int*)d_in[1];
  const float* lg = (const float*)d_in[2];
  const float* lu = (const float*)d_in[3];
  const float* ld = (const float*)d_in[4];
  const float* vg = (const float*)d_in[5];
  const float* vu = (const float*)d_in[6];
  const float* vd = (const float*)d_in[7];

  u16* ws  = (u16*)d_ws;
  u16* xbf = ws;                        // 4096*4096            = 16,777,216
  u16* GUl = xbf + 16777216;            // 22016*4096           = 90,177,536
  u16* GUv = GUl + 90177536;
  u16* ldT = GUv + 90177536;            // 4096*11008           = 45,088,768
  u16* vdT = ldT + 45088768;
  u16* hbuf = vdT + 45088768;           // 4096*11008
  int* qcnt = (int*)(hbuf + 45088768);  // 4-byte work-queue counter
  // total: ~665 MB + 4 B

  hipMemsetAsync(qcnt, 0, 4, stream);
  cvt_x_kernel<<<dim3(8192), dim3(256), 0, stream>>>(x, xbf);
  transpose_cvt_kernel<<<dim3(11008, 6), dim3(256), 0, stream>>>(
      lg, lu, vg, vu, ld, vd, GUl, GUv, ldT, vdT);
  gemm_gateup_persist<<<dim3(256), dim3(512), 0, stream>>>(
      xbf, GUl, GUv, tt, hbuf, qcnt);
  gemm_down<<<dim3(256), dim3(512), 0, stream>>>(hbuf, ldT, vdT, tt, (float*)d_out);
}

// Round 7
// 1362.448 us; speedup vs baseline: 1.0352x; 1.0352x over previous
//
#include <hip/hip_runtime.h>
#include <math.h>

typedef unsigned short u16;
typedef short s16x8 __attribute__((ext_vector_type(8)));
typedef float f32x16 __attribute__((ext_vector_type(16)));

#define GLOAD16(gp, lp)                                                        \
  __builtin_amdgcn_global_load_lds(                                            \
      (const __attribute__((address_space(1))) void*)(gp),                     \
      (__attribute__((address_space(3))) void*)(lp), 16, 0, 0)

__device__ __forceinline__ u16 f2bf(float f) {
  union { float f; unsigned u; } v; v.f = f;
  unsigned r = v.u + 0x7fffu + ((v.u >> 16) & 1u);  // RNE
  return (u16)(r >> 16);
}

// ---------------- kernel 1: x fp32 -> bf16 ----------------
__global__ __launch_bounds__(256) void cvt_x_kernel(const float* __restrict__ in,
                                                    u16* __restrict__ out) {
  size_t i = ((size_t)blockIdx.x * 256 + threadIdx.x) * 8;
  float4 a = *(const float4*)(in + i);
  float4 b = *(const float4*)(in + i + 4);
  s16x8 v;
  v[0] = (short)f2bf(a.x); v[1] = (short)f2bf(a.y);
  v[2] = (short)f2bf(a.z); v[3] = (short)f2bf(a.w);
  v[4] = (short)f2bf(b.x); v[5] = (short)f2bf(b.y);
  v[6] = (short)f2bf(b.z); v[7] = (short)f2bf(b.w);
  *(s16x8*)(out + i) = v;
}

// ------- kernel 2: transpose+cvt. mats 0-3 (g/u) -> interleaved GU with
// 128-row blocking: GU row = (f>>7)*256 + t*128 + (f&127), t=0 gate, 1 up.
// mats 4,5 plain transpose.
__global__ __launch_bounds__(256) void transpose_cvt_kernel(
    const float* __restrict__ in0, const float* __restrict__ in1,
    const float* __restrict__ in2, const float* __restrict__ in3,
    const float* __restrict__ in4, const float* __restrict__ in5,
    u16* __restrict__ o01, u16* __restrict__ o23,
    u16* __restrict__ o4, u16* __restrict__ o5) {
  __shared__ float s[64 * 65];
  const int mat = blockIdx.y;
  const float* in; u16* out;
  switch (mat) {
    case 0: in = in0; out = o01; break;
    case 1: in = in1; out = o01; break;
    case 2: in = in2; out = o23; break;
    case 3: in = in3; out = o23; break;
    case 4: in = in4; out = o4; break;
    default: in = in5; out = o5; break;
  }
  const int R = (mat < 4) ? 4096 : 11008;
  const int C = (mat < 4) ? 11008 : 4096;
  const int nTc = C >> 6;
  const int tr = blockIdx.x / nTc, tc = blockIdx.x - tr * nTc;
  const int r0 = tr << 6, c0 = tc << 6;
  const int t = threadIdx.x;
#pragma unroll
  for (int p = 0; p < 4; ++p) {
    const int lr = p * 16 + (t >> 4);
    const int lc = (t & 15) * 4;
    float4 v = *(const float4*)(in + (size_t)(r0 + lr) * C + (c0 + lc));
    float* sp = &s[lr * 65 + lc];
    sp[0] = v.x; sp[1] = v.y; sp[2] = v.z; sp[3] = v.w;
  }
  __syncthreads();
#pragma unroll
  for (int q = 0; q < 2; ++q) {
    const int oc = q * 32 + (t >> 3);
    const int orr = (t & 7) * 8;
    s16x8 v;
#pragma unroll
    for (int i = 0; i < 8; ++i) v[i] = (short)f2bf(s[(orr + i) * 65 + oc]);
    const int f = c0 + oc;
    size_t orow;
    if (mat < 4) orow = (size_t)((f >> 7) << 8) + ((mat & 1) << 7) + (f & 127);
    else         orow = (size_t)f;
    *(s16x8*)(out + orow * R + (r0 + orr)) = v;
  }
}

// ======== 256x256 GEMM core: 32x32x16 MFMA, round-5 8-phase ledger ==========
// 8 waves (2M x 4N). Per wave: 2 mh x 2 fj m-frags (32 rows), 2 nh n-frags
// (32 cols). Frag-once ds_reads. LDS [2buf][2half][128][64] u16 per operand.
// Swizzle: storage chunk = logical ^ f(r), f(r) = (r&7) ^ ((r>>3)&3) —
// 4-way-conflict-free for the 32x32 read pattern (lanes x,x+8,x+16,x+24 get
// distinct chunks). Applied on pre-swizzled global source + read address.
// Schedule per 2 K-tiles (8 phases): reads P1{af(mh0),bf0} P2{bf1} P3{af(mh1)}
// P4{} (mirror P5-P8 on buf1); stages 1 half/phase: A1'(T+1)@P1, A0'(T+2)@P2,
// B0'@P3, B1'@P4, A1'(T+2)@P5, A0'(T+3)@P6, B0'@P7, B1'@P8; vmcnt(6)@P4/P8.
#define SBAR() __builtin_amdgcn_s_barrier()
#define LGKM0() asm volatile("s_waitcnt lgkmcnt(0)")
#define LGKM8() asm volatile("s_waitcnt lgkmcnt(8)")
#define VMCNT6() asm volatile("s_waitcnt vmcnt(6)")
#define VMCNT0() asm volatile("s_waitcnt vmcnt(0)")

#define LDA(d, mh)                                                             \
  do {                                                                         \
    _Pragma("unroll") for (int fj = 0; fj < 2; ++fj)                           \
        _Pragma("unroll") for (int ks = 0; ks < 4; ++ks)                       \
        af[fj][ks] = *(const s16x8*)(ldsA + (d) * 32768 + (mh) * 16384 +       \
                                     arow + fj * 4096 + cx[ks]);               \
  } while (0)
#define LDB(d, nh)                                                             \
  do {                                                                         \
    _Pragma("unroll") for (int ks = 0; ks < 4; ++ks)                           \
        bf[nh][ks] = *(const s16x8*)(ldsB + (d) * 32768 + (nh) * 16384 +       \
                                     brow + cx[ks]);                           \
  } while (0)
#define MFMA8(mh, nh)                                                          \
  do {                                                                         \
    __builtin_amdgcn_s_setprio(1);                                             \
    _Pragma("unroll") for (int fj = 0; fj < 2; ++fj)                           \
        _Pragma("unroll") for (int ks = 0; ks < 4; ++ks)                       \
        acc[mh][fj][nh] = __builtin_amdgcn_mfma_f32_32x32x16_bf16(             \
            af[fj][ks], bf[nh][ks], acc[mh][fj][nh], 0, 0, 0);                 \
    __builtin_amdgcn_s_setprio(0);                                             \
  } while (0)

#define STG_A(d, h, kt)                                                        \
  do {                                                                         \
    GLOAD16(srcA + (size_t)((h) * 128) * KB + (size_t)(kt) * 128,              \
            ldsA + (d) * 32768 + (h) * 16384 + woff);                          \
    GLOAD16(srcA + (size_t)((h) * 128 + 64) * KB + (size_t)(kt) * 128,         \
            ldsA + (d) * 32768 + (h) * 16384 + 8192 + woff);                   \
  } while (0)
#define STG_B(d, h, kt)                                                        \
  do {                                                                         \
    GLOAD16(srcB + (size_t)((h) * 128) * KB + (size_t)(kt) * 128,              \
            ldsB + (d) * 32768 + (h) * 16384 + woff);                          \
    GLOAD16(srcB + (size_t)((h) * 128 + 64) * KB + (size_t)(kt) * 128,         \
            ldsB + (d) * 32768 + (h) * 16384 + 8192 + woff);                   \
  } while (0)

// body shared by both GEMMs: full 64-K-tile... (per-tile; NKT must be even)
#define GEMM_PIPE(NKT)                                                         \
  do {                                                                         \
    STG_A(0, 0, 0); STG_B(0, 0, 0); STG_B(0, 1, 0); STG_A(0, 1, 0);            \
    STG_A(1, 0, 1); STG_B(1, 0, 1); STG_B(1, 1, 1);                            \
    VMCNT6();                                                                  \
    SBAR();                                                                    \
    for (int T = 0; T < (NKT)-2; T += 2) {                                     \
      LDA(0, 0); LDB(0, 0);                                                    \
      STG_A(1, 1, T + 1);                                                      \
      LGKM8();                                                                 \
      SBAR(); LGKM0(); MFMA8(0, 0); SBAR();                                    \
      LDB(0, 1);                                                               \
      STG_A(0, 0, T + 2);                                                      \
      SBAR(); LGKM0(); MFMA8(0, 1); SBAR();                                    \
      LDA(0, 1);                                                               \
      STG_B(0, 0, T + 2);                                                      \
      SBAR(); LGKM0(); MFMA8(1, 1); SBAR();                                    \
      STG_B(0, 1, T + 2);                                                      \
      VMCNT6();                                                                \
      SBAR(); MFMA8(1, 0); SBAR();                                             \
      LDA(1, 0); LDB(1, 0);                                                    \
      STG_A(0, 1, T + 2);                                                      \
      LGKM8();                                                                 \
      SBAR(); LGKM0(); MFMA8(0, 0); SBAR();                                    \
      LDB(1, 1);                                                               \
      STG_A(1, 0, T + 3);                                                      \
      SBAR(); LGKM0(); MFMA8(0, 1); SBAR();                                    \
      LDA(1, 1);                                                               \
      STG_B(1, 0, T + 3);                                                      \
      SBAR(); LGKM0(); MFMA8(1, 1); SBAR();                                    \
      STG_B(1, 1, T + 3);                                                      \
      VMCNT6();                                                                \
      SBAR(); MFMA8(1, 0); SBAR();                                             \
    }                                                                          \
    LDA(0, 0); LDB(0, 0);                                                      \
    STG_A(1, 1, (NKT)-1);                                                      \
    LGKM8();                                                                   \
    SBAR(); LGKM0(); MFMA8(0, 0); SBAR();                                      \
    LDB(0, 1);                                                                 \
    SBAR(); LGKM0(); MFMA8(0, 1); SBAR();                                      \
    LDA(0, 1);                                                                 \
    SBAR(); LGKM0(); MFMA8(1, 1); SBAR();                                      \
    VMCNT0();                                                                  \
    SBAR(); MFMA8(1, 0); SBAR();                                               \
    LDA(1, 0); LDB(1, 0);                                                      \
    LGKM8();                                                                   \
    SBAR(); LGKM0(); MFMA8(0, 0); SBAR();                                      \
    LDB(1, 1);                                                                 \
    SBAR(); LGKM0(); MFMA8(0, 1); SBAR();                                      \
    LDA(1, 1);                                                                 \
    SBAR(); LGKM0(); MFMA8(1, 1); SBAR();                                      \
    MFMA8(1, 0);                                                               \
  } while (0)

// ---------------- persistent gate+up GEMM + silu (atomic work queue) --------
__global__ __launch_bounds__(512, 1) void gemm_gateup_persist(
    const u16* __restrict__ A, const u16* __restrict__ GUl,
    const u16* __restrict__ GUv, const int* __restrict__ tt,
    u16* __restrict__ H, int* __restrict__ qcnt) {
  constexpr int KB = 8192;  // bytes per K-row
  __shared__ u16 sA[2][2][128][64];
  __shared__ u16 sB[2][2][128][64];
  __shared__ int sQ;

  const int t = threadIdx.x;
  const int lane = t & 63;
  const int l31 = lane & 31;
  const int kg = lane >> 5;
  const int wn = (t >> 6) & 3;
  const int wm = (t >> 8) & 1;

  const int rowq = t >> 3;
  const int gsw = ((t & 7) ^ (rowq & 7) ^ ((rowq >> 3) & 3)) << 4;
  char* ldsA = (char*)&sA[0][0][0][0];
  char* ldsB = (char*)&sB[0][0][0][0];
  const int woff = (t & 448) << 4;

  const int arow = (wm * 64 + l31) * 128;
  const int brow = (wn * 32 + l31) * 128;
  int cx[4];
#pragma unroll
  for (int ks = 0; ks < 4; ++ks)
    cx[ks] = ((2 * ks + kg) ^ (l31 & 7) ^ ((l31 >> 3) & 3)) << 4;

  for (;;) {
    __syncthreads();
    if (t == 0) sQ = atomicAdd(qcnt, 1);
    __syncthreads();
    const int q = sQ;
    if (q >= 1376) break;
    const int nT = q >> 4;
    const int mT = q & 15;
    const int side = tt[mT << 8];
    const u16* GU = side ? GUl : GUv;
    const char* srcA = (const char*)A + (size_t)(mT * 256 + rowq) * KB + gsw;
    const char* srcB = (const char*)GU + (size_t)(nT * 256 + rowq) * KB + gsw;

    s16x8 af[2][4], bf[2][4];
    f32x16 acc[2][2][2];
#pragma unroll
    for (int a = 0; a < 2; ++a)
#pragma unroll
      for (int b = 0; b < 2; ++b)
#pragma unroll
        for (int c2 = 0; c2 < 2; ++c2)
#pragma unroll
          for (int r = 0; r < 16; ++r) acc[a][b][c2][r] = 0.f;

    GEMM_PIPE(64);

    // epilogue: silu(gate)*up -> H (nh0 = gate, nh1 = up; same f in-lane)
    const int f = nT * 128 + wn * 32 + l31;
#pragma unroll
    for (int mh = 0; mh < 2; ++mh)
#pragma unroll
      for (int fj = 0; fj < 2; ++fj) {
        const int rowbase = mT * 256 + mh * 128 + wm * 64 + fj * 32 + 4 * kg;
#pragma unroll
        for (int r = 0; r < 16; ++r) {
          const int row = rowbase + (r & 3) + 8 * (r >> 2);
          const float gv = acc[mh][fj][0][r];
          const float uv = acc[mh][fj][1][r];
          const float hv = gv / (1.f + __expf(-gv)) * uv;
          H[(size_t)row * 11008 + f] = f2bf(hv);
        }
      }
  }
}

// ---------------- down GEMM (static 1 tile/block) ----------------
__global__ __launch_bounds__(512, 1) void gemm_down(
    const u16* __restrict__ Hm, const u16* __restrict__ Dl,
    const u16* __restrict__ Dv, const int* __restrict__ tt,
    float* __restrict__ O) {
  constexpr int KB = 22016;  // bytes per K-row
  __shared__ u16 sA[2][2][128][64];
  __shared__ u16 sB[2][2][128][64];

  const int bid = blockIdx.x;
  const int wg = (bid & 7) * 32 + (bid >> 3);  // bijective XCD swizzle
  const int mT = wg & 15;
  const int nT = wg >> 4;

  const int t = threadIdx.x;
  const int lane = t & 63;
  const int l31 = lane & 31;
  const int kg = lane >> 5;
  const int wn = (t >> 6) & 3;
  const int wm = (t >> 8) & 1;

  const int side = tt[mT << 8];
  const u16* B = side ? Dl : Dv;

  const int rowq = t >> 3;
  const int gsw = ((t & 7) ^ (rowq & 7) ^ ((rowq >> 3) & 3)) << 4;
  const char* srcA = (const char*)Hm + (size_t)(mT * 256 + rowq) * KB + gsw;
  const char* srcB = (const char*)B + (size_t)(nT * 256 + rowq) * KB + gsw;
  char* ldsA = (char*)&sA[0][0][0][0];
  char* ldsB = (char*)&sB[0][0][0][0];
  const int woff = (t & 448) << 4;

  const int arow = (wm * 64 + l31) * 128;
  const int brow = (wn * 32 + l31) * 128;
  int cx[4];
#pragma unroll
  for (int ks = 0; ks < 4; ++ks)
    cx[ks] = ((2 * ks + kg) ^ (l31 & 7) ^ ((l31 >> 3) & 3)) << 4;

  s16x8 af[2][4], bf[2][4];
  f32x16 acc[2][2][2];
#pragma unroll
  for (int a = 0; a < 2; ++a)
#pragma unroll
    for (int b = 0; b < 2; ++b)
#pragma unroll
      for (int c2 = 0; c2 < 2; ++c2)
#pragma unroll
        for (int r = 0; r < 16; ++r) acc[a][b][c2][r] = 0.f;

  GEMM_PIPE(172);

#pragma unroll
  for (int mh = 0; mh < 2; ++mh)
#pragma unroll
    for (int fj = 0; fj < 2; ++fj) {
      const int rowbase = mT * 256 + mh * 128 + wm * 64 + fj * 32 + 4 * kg;
#pragma unroll
      for (int nh = 0; nh < 2; ++nh) {
        const int col = nT * 256 + nh * 128 + wn * 32 + l31;
#pragma unroll
        for (int r = 0; r < 16; ++r) {
          const int row = rowbase + (r & 3) + 8 * (r >> 2);
          O[(size_t)row * 4096 + col] = acc[mh][fj][nh][r];
        }
      }
    }
}

extern "C" void kernel_launch(void* const* d_in, const int* in_sizes, int n_in,
                              void* d_out, int out_size, void* d_ws, size_t ws_size,
                              hipStream_t stream) {
  (void)in_sizes; (void)n_in; (void)out_size; (void)ws_size;
  const float* x  = (const float*)d_in[0];
  const int*   tt = (const int*)d_in[1];
  const float* lg = (const float*)d_in[2];
  const float* lu = (const float*)d_in[3];
  const float* ld = (const float*)d_in[4];
  const float* vg = (const float*)d_in[5];
  const float* vu = (const float*)d_in[6];
  const float* vd = (const float*)d_in[7];

  u16* ws  = (u16*)d_ws;
  u16* xbf = ws;                        // 4096*4096            = 16,777,216
  u16* GUl = xbf + 16777216;            // 22016*4096           = 90,177,536
  u16* GUv = GUl + 90177536;
  u16* ldT = GUv + 90177536;            // 4096*11008           = 45,088,768
  u16* vdT = ldT + 45088768;
  u16* hbuf = vdT + 45088768;           // 4096*11008
  int* qcnt = (int*)(hbuf + 45088768);  // 4-byte work-queue counter
  // total: ~665 MB + 4 B

  hipMemsetAsync(qcnt, 0, 4, stream);
  cvt_x_kernel<<<dim3(8192), dim3(256), 0, stream>>>(x, xbf);
  transpose_cvt_kernel<<<dim3(11008, 6), dim3(256), 0, stream>>>(
      lg, lu, vg, vu, ld, vd, GUl, GUv, ldT, vdT);
  gemm_gateup_persist<<<dim3(256), dim3(512), 0, stream>>>(
      xbf, GUl, GUv, tt, hbuf, qcnt);
  gemm_down<<<dim3(256), dim3(512), 0, stream>>>(hbuf, ldT, vdT, tt, (float*)d_out);
}